// Round 3
// baseline (468.074 us; speedup 1.0000x reference)
//
#include <hip/hip_runtime.h>
#include <math.h>

#define NS 8192
#define DS 64
#define HD 4096
#define C2L 2.8853900817779268f   // 2*log2(e)

typedef float v2f __attribute__((ext_vector_type(2)));

// guaranteed packed-fp32 (gfx90a+/gfx950 full-rate: 2 fp32 per 2-cycle wave64 issue)
__device__ __forceinline__ v2f pk_add(v2f a, v2f b) {
    v2f d; asm("v_pk_add_f32 %0, %1, %2" : "=v"(d) : "v"(a), "v"(b)); return d;
}
__device__ __forceinline__ v2f pk_mul(v2f a, v2f b) {
    v2f d; asm("v_pk_mul_f32 %0, %1, %2" : "=v"(d) : "v"(a), "v"(b)); return d;
}
__device__ __forceinline__ v2f pk_fma(v2f a, v2f b, v2f c) {
    v2f d; asm("v_pk_fma_f32 %0, %1, %2, %3" : "=v"(d) : "v"(a), "v"(b), "v"(c)); return d;
}

__device__ __forceinline__ float fast_tanh(float x) {
    float t = __builtin_amdgcn_exp2f(x * C2L);
    float r = __builtin_amdgcn_rcpf(t + 1.0f);
    return __builtin_fmaf(-2.0f, r, 1.0f);
}

// ---- setup: E+/E- = e^{+-2*W1}; C01 = colsum(W2) + b2 ----
__global__ __launch_bounds__(256) void qnade_prep_E(
    const float* __restrict__ W1, float* __restrict__ Ep, float* __restrict__ Em)
{
    int i = blockIdx.x * 256 + threadIdx.x;
    float w = W1[i] * C2L;
    Ep[i] = __builtin_amdgcn_exp2f(w);
    Em[i] = __builtin_amdgcn_exp2f(-w);
}

__global__ __launch_bounds__(256) void qnade_prep_S(
    const float* __restrict__ W2, const float* __restrict__ b2, float* __restrict__ C01)
{
    __shared__ float p0[4], p1[4];
    int tid = threadIdx.x;
    float s0 = 0.0f, s1 = 0.0f;
    for (int h = tid; h < HD; h += 256) {
        float2 w = ((const float2*)W2)[h];
        s0 += w.x; s1 += w.y;
    }
    #pragma unroll
    for (int m = 1; m < 64; m <<= 1) {
        s0 += __shfl_xor(s0, m, 64);
        s1 += __shfl_xor(s1, m, 64);
    }
    if ((tid & 63) == 0) { p0[tid >> 6] = s0; p1[tid >> 6] = s1; }
    __syncthreads();
    if (tid == 0) {
        C01[0] = p0[0] + p0[1] + p0[2] + p0[3] + b2[0];
        C01[1] = p1[0] + p1[1] + p1[2] + p1[3] + b2[1];
    }
}

// ---- main: one block = one sample; 4 waves x 1024 hidden each ----
// state t = e^{2a}; t *= E[d]; r = 1/(1+t) via Montgomery batch-of-16 (1 rcp);
// dot = C01 - 2*sum(r*w2). Epilogue deferred to after the d-loop.
__global__ __launch_bounds__(256) void qnade_main(
    const float* __restrict__ x, const float* __restrict__ b1,
    const float* __restrict__ W2, const float* __restrict__ Ep,
    const float* __restrict__ Em, const float* __restrict__ C01,
    float* __restrict__ out)
{
    __shared__ float parts[DS * 64];   // 16 KB

    const int tid  = threadIdx.x;
    const int lane = tid & 63;
    const int wv   = tid >> 6;
    const int n    = blockIdx.x;
    const int hbase = wv * 1024 + lane * 4;   // + q*256 + c

    // W2 columns as (even,odd)-element pairs
    v2f w20[8], w21[8];
    #pragma unroll
    for (int q = 0; q < 4; ++q) {
        const float4* p = (const float4*)(W2 + 2 * (hbase + q * 256));
        float4 A = p[0], B = p[1];
        w20[2*q]   = (v2f){A.x, A.z};  w21[2*q]   = (v2f){A.y, A.w};
        w20[2*q+1] = (v2f){B.x, B.z};  w21[2*q+1] = (v2f){B.y, B.w};
    }

    // t0 = e^{2*b1}, paired (elem 4q+0,4q+1) | (4q+2,4q+3)
    v2f t2[8];
    #pragma unroll
    for (int q = 0; q < 4; ++q) {
        float4 b = *(const float4*)(b1 + hbase + q * 256);
        t2[2*q]   = (v2f){__builtin_amdgcn_exp2f(b.x * C2L), __builtin_amdgcn_exp2f(b.y * C2L)};
        t2[2*q+1] = (v2f){__builtin_amdgcn_exp2f(b.z * C2L), __builtin_amdgcn_exp2f(b.w * C2L)};
    }

    const float xv = x[n * DS + lane];
    const unsigned long long msk = __ballot(xv > 0.0f);   // spin signs, one scalar per wave
    const v2f one = (v2f){1.0f, 1.0f};

    #pragma unroll 1
    for (int d = 0; d < DS; ++d) {
        const float* E = (((msk >> d) & 1ull) ? Ep : Em) + d * HD + hbase;  // wave-uniform
        float4 e0 = *(const float4*)(E);
        float4 e1 = *(const float4*)(E + 256);
        float4 e2 = *(const float4*)(E + 512);
        float4 e3 = *(const float4*)(E + 768);

        // u = 1 + t
        v2f u2[8], p2[8];
        #pragma unroll
        for (int j = 0; j < 8; ++j) u2[j] = pk_add(t2[j], one);
        // prefix products (two independent chains packed)
        p2[0] = u2[0];
        #pragma unroll
        for (int j = 1; j < 8; ++j) p2[j] = pk_mul(p2[j - 1], u2[j]);
        // single reciprocal for all 16
        float P = p2[7].x * p2[7].y;
        float R = __builtin_amdgcn_rcpf(P);
        v2f RR = (v2f){R * p2[7].y, R * p2[7].x};
        // recovery
        v2f r2[8];
        #pragma unroll
        for (int j = 7; j >= 1; --j) {
            r2[j] = pk_mul(RR, p2[j - 1]);
            RR    = pk_mul(RR, u2[j]);
        }
        r2[0] = RR;

        // dot accumulation (pairwise), and t update
        v2f acc0 = (v2f){0.0f, 0.0f}, acc1 = (v2f){0.0f, 0.0f};
        #pragma unroll
        for (int j = 0; j < 8; ++j) {
            acc0 = pk_fma(r2[j], w20[j], acc0);
            acc1 = pk_fma(r2[j], w21[j], acc1);
        }
        t2[0] = pk_mul(t2[0], (v2f){e0.x, e0.y});
        t2[1] = pk_mul(t2[1], (v2f){e0.z, e0.w});
        t2[2] = pk_mul(t2[2], (v2f){e1.x, e1.y});
        t2[3] = pk_mul(t2[3], (v2f){e1.z, e1.w});
        t2[4] = pk_mul(t2[4], (v2f){e2.x, e2.y});
        t2[5] = pk_mul(t2[5], (v2f){e2.z, e2.w});
        t2[6] = pk_mul(t2[6], (v2f){e3.x, e3.y});
        t2[7] = pk_mul(t2[7], (v2f){e3.z, e3.w});

        float a0 = acc0.x + acc0.y;
        float a1 = acc1.x + acc1.y;
        a0 += __shfl_xor(a0, 8, 64);
        a0 += __shfl_xor(a0, 16, 64);
        a0 += __shfl_xor(a0, 32, 64);
        a1 += __shfl_xor(a1, 8, 64);
        a1 += __shfl_xor(a1, 16, 64);
        a1 += __shfl_xor(a1, 32, 64);
        if (lane < 8) {
            parts[d * 64 + wv * 16 + lane]     = a0;
            parts[d * 64 + wv * 16 + 8 + lane] = a1;
        }
    }

    __syncthreads();

    // deferred epilogue: wave 0, lane d handles step d
    if (tid < DS) {
        const int d = tid;
        const float* p = parts + d * 64;
        float s0 = 0.0f, s1 = 0.0f;
        #pragma unroll
        for (int w = 0; w < 4; ++w) {
            #pragma unroll
            for (int i = 0; i < 8; ++i) {
                s0 += p[w * 16 + i];
                s1 += p[w * 16 + 8 + i];
            }
        }
        float dot0 = __builtin_fmaf(-2.0f, s0, C01[0]);
        float dot1 = __builtin_fmaf(-2.0f, s1, C01[1]);
        float o0 = fast_tanh(dot0);
        float o1 = fast_tanh(dot1);
        float nrm = sqrtf(__builtin_fmaf(o0, o0, o1 * o1));
        nrm = fmaxf(nrm, 1e-12f);
        float sel = (x[n * DS + d] > 0.0f) ? o0 : o1;
        float v = sel * __builtin_amdgcn_rcpf(nrm);
        v *= __shfl_xor(v, 1, 64);
        v *= __shfl_xor(v, 2, 64);
        v *= __shfl_xor(v, 4, 64);
        v *= __shfl_xor(v, 8, 64);
        v *= __shfl_xor(v, 16, 64);
        v *= __shfl_xor(v, 32, 64);
        if (tid == 0) out[n] = v;
    }
}

// ---- fallback if ws too small ----
__global__ __launch_bounds__(256) void qnade_fallback(
    const float* __restrict__ x, const float* __restrict__ W1,
    const float* __restrict__ b1, const float* __restrict__ W2,
    const float* __restrict__ b2, float* __restrict__ out)
{
    __shared__ __align__(16) float w20s[HD];
    __shared__ __align__(16) float w21s[HD];
    const int tid = threadIdx.x;
    for (int i = tid; i < HD; i += 256) {
        float2 w = ((const float2*)W2)[i];
        w20s[i] = w.x;
        w21s[i] = w.y;
    }
    const int lane = tid & 63;
    const int wv   = tid >> 6;
    const int n    = (blockIdx.x << 2) + wv;
    const float b20 = b2[0];
    const float b21 = b2[1];
    const float xv = x[n * DS + lane];
    float4 a[16];
    const float4* b1v = (const float4*)b1;
    #pragma unroll
    for (int q = 0; q < 16; ++q) a[q] = b1v[q * 64 + lane];
    __syncthreads();
    const float4* w20v = (const float4*)w20s;
    const float4* w21v = (const float4*)w21s;
    float wav = 1.0f;
    for (int d = 0; d < DS; ++d) {
        const float xd = __shfl(xv, d, 64);
        const float4* w1v = (const float4*)(W1 + d * HD);
        float dot0 = 0.0f, dot1 = 0.0f;
        #pragma unroll
        for (int q = 0; q < 16; ++q) {
            float4 w1 = w1v[q * 64 + lane];
            float4 av = a[q];
            float h0 = fast_tanh(av.x);
            float h1 = fast_tanh(av.y);
            float h2 = fast_tanh(av.z);
            float h3 = fast_tanh(av.w);
            float4 c0 = w20v[q * 64 + lane];
            float4 c1 = w21v[q * 64 + lane];
            dot0 = fmaf(h0, c0.x, dot0); dot0 = fmaf(h1, c0.y, dot0);
            dot0 = fmaf(h2, c0.z, dot0); dot0 = fmaf(h3, c0.w, dot0);
            dot1 = fmaf(h0, c1.x, dot1); dot1 = fmaf(h1, c1.y, dot1);
            dot1 = fmaf(h2, c1.z, dot1); dot1 = fmaf(h3, c1.w, dot1);
            av.x = fmaf(xd, w1.x, av.x); av.y = fmaf(xd, w1.y, av.y);
            av.z = fmaf(xd, w1.z, av.z); av.w = fmaf(xd, w1.w, av.w);
            a[q] = av;
        }
        #pragma unroll
        for (int m = 1; m < 64; m <<= 1) {
            dot0 += __shfl_xor(dot0, m, 64);
            dot1 += __shfl_xor(dot1, m, 64);
        }
        float o0 = fast_tanh(dot0 + b20);
        float o1 = fast_tanh(dot1 + b21);
        float nrm = sqrtf(fmaf(o0, o0, o1 * o1));
        nrm = fmaxf(nrm, 1e-12f);
        float sel = (xd > 0.0f) ? o0 : o1;
        wav *= sel / nrm;
    }
    out[n] = wav;
}

extern "C" void kernel_launch(void* const* d_in, const int* in_sizes, int n_in,
                              void* d_out, int out_size, void* d_ws, size_t ws_size,
                              hipStream_t stream) {
    const float* x  = (const float*)d_in[0];
    const float* W1 = (const float*)d_in[1];
    const float* b1 = (const float*)d_in[2];
    const float* W2 = (const float*)d_in[3];
    const float* b2 = (const float*)d_in[4];
    float* out = (float*)d_out;

    const size_t need = (size_t)(2 * DS * HD + 2) * sizeof(float);
    if (ws_size >= need) {
        float* Ep  = (float*)d_ws;
        float* Em  = Ep + DS * HD;
        float* C01 = Em + DS * HD;
        hipLaunchKernelGGL(qnade_prep_E, dim3(DS * HD / 256), dim3(256), 0, stream, W1, Ep, Em);
        hipLaunchKernelGGL(qnade_prep_S, dim3(1), dim3(256), 0, stream, W2, b2, C01);
        hipLaunchKernelGGL(qnade_main, dim3(NS), dim3(256), 0, stream, x, b1, W2, Ep, Em, C01, out);
    } else {
        hipLaunchKernelGGL(qnade_fallback, dim3(NS / 4), dim3(256), 0, stream, x, W1, b1, W2, b2, out);
    }
}

// Round 4
// 458.273 us; speedup vs baseline: 1.0214x; 1.0214x over previous
//
#include <hip/hip_runtime.h>
#include <math.h>

#define NS 8192
#define DS 64
#define HD 4096
#define C2L 2.8853900817779268f   // 2*log2(e)

typedef float v2f __attribute__((ext_vector_type(2)));

// packed fp32 (4 cyc/wave64 — same FLOP rate as scalar, half the instructions)
__device__ __forceinline__ v2f pk_add(v2f a, v2f b) {
    v2f d; asm("v_pk_add_f32 %0, %1, %2" : "=v"(d) : "v"(a), "v"(b)); return d;
}
__device__ __forceinline__ v2f pk_mul(v2f a, v2f b) {
    v2f d; asm("v_pk_mul_f32 %0, %1, %2" : "=v"(d) : "v"(a), "v"(b)); return d;
}
__device__ __forceinline__ v2f pk_fma(v2f a, v2f b, v2f c) {
    v2f d; asm("v_pk_fma_f32 %0, %1, %2, %3" : "=v"(d) : "v"(a), "v"(b), "v"(c)); return d;
}

__device__ __forceinline__ float fast_tanh(float x) {
    float t = __builtin_amdgcn_exp2f(x * C2L);
    float r = __builtin_amdgcn_rcpf(t + 1.0f);
    return __builtin_fmaf(-2.0f, r, 1.0f);
}

__device__ __forceinline__ float swz_xor16(float v) {
    return __int_as_float(__builtin_amdgcn_ds_swizzle(__float_as_int(v), 0x401F));
}
__device__ __forceinline__ float swz_xor8(float v) {
    return __int_as_float(__builtin_amdgcn_ds_swizzle(__float_as_int(v), 0x201F));
}
__device__ __forceinline__ float bperm(int addr, float v) {
    return __int_as_float(__builtin_amdgcn_ds_bpermute(addr, __float_as_int(v)));
}

// ---- setup: E+/E- = e^{+-2*W1}; C01 = colsum(W2) + b2 ----
__global__ __launch_bounds__(256) void qnade_prep_E(
    const float* __restrict__ W1, float* __restrict__ Ep, float* __restrict__ Em)
{
    int i = blockIdx.x * 256 + threadIdx.x;
    float w = W1[i] * C2L;
    Ep[i] = __builtin_amdgcn_exp2f(w);
    Em[i] = __builtin_amdgcn_exp2f(-w);
}

__global__ __launch_bounds__(256) void qnade_prep_S(
    const float* __restrict__ W2, const float* __restrict__ b2, float* __restrict__ C01)
{
    __shared__ float p0[4], p1[4];
    int tid = threadIdx.x;
    float s0 = 0.0f, s1 = 0.0f;
    for (int h = tid; h < HD; h += 256) {
        float2 w = ((const float2*)W2)[h];
        s0 += w.x; s1 += w.y;
    }
    #pragma unroll
    for (int m = 1; m < 64; m <<= 1) {
        s0 += __shfl_xor(s0, m, 64);
        s1 += __shfl_xor(s1, m, 64);
    }
    if ((tid & 63) == 0) { p0[tid >> 6] = s0; p1[tid >> 6] = s1; }
    __syncthreads();
    if (tid == 0) {
        C01[0] = p0[0] + p0[1] + p0[2] + p0[3] + b2[0];
        C01[1] = p1[0] + p1[1] + p1[2] + p1[3] + b2[1];
    }
}

// ---- main: one block = one sample; 4 waves x 1024 hidden each ----
// state t = e^{2a}; t *= E[d]; batch inversion with u=1+t folded into fmas:
//   p_j = p_{j-1}*(1+t_j) = fma(p_{j-1}, t_j, p_{j-1})
// dot = C01 - 2*sum(w2/(1+t)); per-step epilogue deferred past the d-loop.
__global__ __launch_bounds__(256) void qnade_main(
    const float* __restrict__ x, const float* __restrict__ b1,
    const float* __restrict__ W2, const float* __restrict__ Ep,
    const float* __restrict__ Em, const float* __restrict__ C01,
    float* __restrict__ out)
{
    __shared__ float parts[DS * 64];   // 16 KB: [d][wv*16 + lane*2 + {0,1}]

    const int tid  = threadIdx.x;
    const int lane = tid & 63;
    const int wv   = tid >> 6;
    const int n    = blockIdx.x;
    const int hbase = wv * 1024 + lane * 4;   // + q*256 + c
    const int bp_addr = ((lane ^ 32) << 2);   // bpermute byte index for xor-32

    // W2 columns as (even,odd)-element pairs
    v2f w20[8], w21[8];
    #pragma unroll
    for (int q = 0; q < 4; ++q) {
        const float4* p = (const float4*)(W2 + 2 * (hbase + q * 256));
        float4 A = p[0], B = p[1];
        w20[2*q]   = (v2f){A.x, A.z};  w21[2*q]   = (v2f){A.y, A.w};
        w20[2*q+1] = (v2f){B.x, B.z};  w21[2*q+1] = (v2f){B.y, B.w};
    }

    // t0 = e^{2*b1}
    v2f t2[8];
    #pragma unroll
    for (int q = 0; q < 4; ++q) {
        float4 b = *(const float4*)(b1 + hbase + q * 256);
        t2[2*q]   = (v2f){__builtin_amdgcn_exp2f(b.x * C2L), __builtin_amdgcn_exp2f(b.y * C2L)};
        t2[2*q+1] = (v2f){__builtin_amdgcn_exp2f(b.z * C2L), __builtin_amdgcn_exp2f(b.w * C2L)};
    }

    const float xv = x[n * DS + lane];
    const unsigned long long msk = __ballot(xv > 0.0f);
    const float* EpL = Ep + hbase;
    const float* EmL = Em + hbase;

    #pragma unroll 2
    for (int d = 0; d < DS; ++d) {
        const float* E = (((msk >> d) & 1ull) ? EpL : EmL) + d * HD;
        float4 e0 = *(const float4*)(E);
        float4 e1 = *(const float4*)(E + 256);
        float4 e2 = *(const float4*)(E + 512);
        float4 e3 = *(const float4*)(E + 768);

        // prefix products of (1+t), u never materialized
        v2f p2[8];
        p2[0] = pk_add(t2[0], (v2f){1.0f, 1.0f});
        #pragma unroll
        for (int j = 1; j < 8; ++j) p2[j] = pk_fma(p2[j - 1], t2[j], p2[j - 1]);

        // one reciprocal for all 16 elements
        float P = p2[7].x * p2[7].y;
        float R = __builtin_amdgcn_rcpf(P);
        v2f RR = (v2f){R * p2[7].y, R * p2[7].x};

        // fused recovery + dot (r consumed as produced)
        v2f acc0, acc1;
        {
            v2f r = pk_mul(RR, p2[6]);
            acc0 = pk_mul(r, w20[7]);
            acc1 = pk_mul(r, w21[7]);
            RR = pk_fma(RR, t2[7], RR);
        }
        #pragma unroll
        for (int j = 6; j >= 1; --j) {
            v2f r = pk_mul(RR, p2[j - 1]);
            acc0 = pk_fma(r, w20[j], acc0);
            acc1 = pk_fma(r, w21[j], acc1);
            RR = pk_fma(RR, t2[j], RR);
        }
        acc0 = pk_fma(RR, w20[0], acc0);
        acc1 = pk_fma(RR, w21[0], acc1);

        // advance state: t *= e  (site d becomes visible for step d+1)
        t2[0] = pk_mul(t2[0], (v2f){e0.x, e0.y});
        t2[1] = pk_mul(t2[1], (v2f){e0.z, e0.w});
        t2[2] = pk_mul(t2[2], (v2f){e1.x, e1.y});
        t2[3] = pk_mul(t2[3], (v2f){e1.z, e1.w});
        t2[4] = pk_mul(t2[4], (v2f){e2.x, e2.y});
        t2[5] = pk_mul(t2[5], (v2f){e2.z, e2.w});
        t2[6] = pk_mul(t2[6], (v2f){e3.x, e3.y});
        t2[7] = pk_mul(t2[7], (v2f){e3.z, e3.w});

        // butterfly: xor32 (bpermute, precomputed addr), xor16/xor8 (swizzle)
        float a0 = acc0.x + acc0.y;
        float a1 = acc1.x + acc1.y;
        a0 += bperm(bp_addr, a0);
        a1 += bperm(bp_addr, a1);
        a0 += swz_xor16(a0);
        a1 += swz_xor16(a1);
        a0 += swz_xor8(a0);
        a1 += swz_xor8(a1);
        if (lane < 8)
            *(float2*)&parts[d * 64 + wv * 16 + lane * 2] = make_float2(a0, a1);
    }

    __syncthreads();

    // deferred epilogue: wave 0, lane d handles step d
    if (tid < DS) {
        const int d = tid;
        const float* p = parts + d * 64;
        float s0 = 0.0f, s1 = 0.0f;
        #pragma unroll
        for (int w = 0; w < 4; ++w) {
            #pragma unroll
            for (int i = 0; i < 8; ++i) {
                s0 += p[w * 16 + 2 * i];
                s1 += p[w * 16 + 2 * i + 1];
            }
        }
        float dot0 = __builtin_fmaf(-2.0f, s0, C01[0]);
        float dot1 = __builtin_fmaf(-2.0f, s1, C01[1]);
        float o0 = fast_tanh(dot0);
        float o1 = fast_tanh(dot1);
        float nrm = sqrtf(__builtin_fmaf(o0, o0, o1 * o1));
        nrm = fmaxf(nrm, 1e-12f);
        float sel = (x[n * DS + d] > 0.0f) ? o0 : o1;
        float v = sel * __builtin_amdgcn_rcpf(nrm);
        v *= __shfl_xor(v, 1, 64);
        v *= __shfl_xor(v, 2, 64);
        v *= __shfl_xor(v, 4, 64);
        v *= __shfl_xor(v, 8, 64);
        v *= __shfl_xor(v, 16, 64);
        v *= __shfl_xor(v, 32, 64);
        if (tid == 0) out[n] = v;
    }
}

// ---- fallback if ws too small ----
__global__ __launch_bounds__(256) void qnade_fallback(
    const float* __restrict__ x, const float* __restrict__ W1,
    const float* __restrict__ b1, const float* __restrict__ W2,
    const float* __restrict__ b2, float* __restrict__ out)
{
    __shared__ __align__(16) float w20s[HD];
    __shared__ __align__(16) float w21s[HD];
    const int tid = threadIdx.x;
    for (int i = tid; i < HD; i += 256) {
        float2 w = ((const float2*)W2)[i];
        w20s[i] = w.x;
        w21s[i] = w.y;
    }
    const int lane = tid & 63;
    const int wv   = tid >> 6;
    const int n    = (blockIdx.x << 2) + wv;
    const float b20 = b2[0];
    const float b21 = b2[1];
    const float xv = x[n * DS + lane];
    float4 a[16];
    const float4* b1v = (const float4*)b1;
    #pragma unroll
    for (int q = 0; q < 16; ++q) a[q] = b1v[q * 64 + lane];
    __syncthreads();
    const float4* w20v = (const float4*)w20s;
    const float4* w21v = (const float4*)w21s;
    float wav = 1.0f;
    for (int d = 0; d < DS; ++d) {
        const float xd = __shfl(xv, d, 64);
        const float4* w1v = (const float4*)(W1 + d * HD);
        float dot0 = 0.0f, dot1 = 0.0f;
        #pragma unroll
        for (int q = 0; q < 16; ++q) {
            float4 w1 = w1v[q * 64 + lane];
            float4 av = a[q];
            float h0 = fast_tanh(av.x);
            float h1 = fast_tanh(av.y);
            float h2 = fast_tanh(av.z);
            float h3 = fast_tanh(av.w);
            float4 c0 = w20v[q * 64 + lane];
            float4 c1 = w21v[q * 64 + lane];
            dot0 = fmaf(h0, c0.x, dot0); dot0 = fmaf(h1, c0.y, dot0);
            dot0 = fmaf(h2, c0.z, dot0); dot0 = fmaf(h3, c0.w, dot0);
            dot1 = fmaf(h0, c1.x, dot1); dot1 = fmaf(h1, c1.y, dot1);
            dot1 = fmaf(h2, c1.z, dot1); dot1 = fmaf(h3, c1.w, dot1);
            av.x = fmaf(xd, w1.x, av.x); av.y = fmaf(xd, w1.y, av.y);
            av.z = fmaf(xd, w1.z, av.z); av.w = fmaf(xd, w1.w, av.w);
            a[q] = av;
        }
        #pragma unroll
        for (int m = 1; m < 64; m <<= 1) {
            dot0 += __shfl_xor(dot0, m, 64);
            dot1 += __shfl_xor(dot1, m, 64);
        }
        float o0 = fast_tanh(dot0 + b20);
        float o1 = fast_tanh(dot1 + b21);
        float nrm = sqrtf(fmaf(o0, o0, o1 * o1));
        nrm = fmaxf(nrm, 1e-12f);
        float sel = (xd > 0.0f) ? o0 : o1;
        wav *= sel / nrm;
    }
    out[n] = wav;
}

extern "C" void kernel_launch(void* const* d_in, const int* in_sizes, int n_in,
                              void* d_out, int out_size, void* d_ws, size_t ws_size,
                              hipStream_t stream) {
    const float* x  = (const float*)d_in[0];
    const float* W1 = (const float*)d_in[1];
    const float* b1 = (const float*)d_in[2];
    const float* W2 = (const float*)d_in[3];
    const float* b2 = (const float*)d_in[4];
    float* out = (float*)d_out;

    const size_t need = (size_t)(2 * DS * HD + 2) * sizeof(float);
    if (ws_size >= need) {
        float* Ep  = (float*)d_ws;
        float* Em  = Ep + DS * HD;
        float* C01 = Em + DS * HD;
        hipLaunchKernelGGL(qnade_prep_E, dim3(DS * HD / 256), dim3(256), 0, stream, W1, Ep, Em);
        hipLaunchKernelGGL(qnade_prep_S, dim3(1), dim3(256), 0, stream, W2, b2, C01);
        hipLaunchKernelGGL(qnade_main, dim3(NS), dim3(256), 0, stream, x, b1, W2, Ep, Em, C01, out);
    } else {
        hipLaunchKernelGGL(qnade_fallback, dim3(NS / 4), dim3(256), 0, stream, x, W1, b1, W2, b2, out);
    }
}

// Round 6
// 423.851 us; speedup vs baseline: 1.1043x; 1.0812x over previous
//
#include <hip/hip_runtime.h>
#include <math.h>

#define NS 8192
#define DS 64
#define HD 4096
#define C2L 2.8853900817779268f   // 2*log2(e)
#define CH 8                      // steps per chunk
#define NCH (DS / CH)

typedef float v2f __attribute__((ext_vector_type(2)));

__device__ __forceinline__ v2f pk_add(v2f a, v2f b) {
    v2f d; asm("v_pk_add_f32 %0, %1, %2" : "=v"(d) : "v"(a), "v"(b)); return d;
}
__device__ __forceinline__ v2f pk_mul(v2f a, v2f b) {
    v2f d; asm("v_pk_mul_f32 %0, %1, %2" : "=v"(d) : "v"(a), "v"(b)); return d;
}
__device__ __forceinline__ v2f pk_fma(v2f a, v2f b, v2f c) {
    v2f d; asm("v_pk_fma_f32 %0, %1, %2, %3" : "=v"(d) : "v"(a), "v"(b), "v"(c)); return d;
}

__device__ __forceinline__ float fast_tanh(float x) {
    float t = __builtin_amdgcn_exp2f(x * C2L);
    float r = __builtin_amdgcn_rcpf(t + 1.0f);
    return __builtin_fmaf(-2.0f, r, 1.0f);
}

// swizzle xor-m on a packed pair; pattern must be an ICE -> template param
template <int PATT>
__device__ __forceinline__ v2f swz_xor(v2f v) {
    v2f d;
    d.x = __int_as_float(__builtin_amdgcn_ds_swizzle(__float_as_int(v.x), PATT));
    d.y = __int_as_float(__builtin_amdgcn_ds_swizzle(__float_as_int(v.y), PATT));
    return d;
}

// ---- setup: Et[0][d][h]=e^{+2W1}, Et[1][d][h]=e^{-2W1}; C01 = colsum(W2)+b2 ----
__global__ __launch_bounds__(256) void qnade_prep_E(
    const float* __restrict__ W1, float* __restrict__ Et)
{
    int i = blockIdx.x * 256 + threadIdx.x;
    float w = W1[i] * C2L;
    Et[i]           = __builtin_amdgcn_exp2f(w);
    Et[DS * HD + i] = __builtin_amdgcn_exp2f(-w);
}

__global__ __launch_bounds__(256) void qnade_prep_S(
    const float* __restrict__ W2, const float* __restrict__ b2, float* __restrict__ C01)
{
    __shared__ float p0[4], p1[4];
    int tid = threadIdx.x;
    float s0 = 0.0f, s1 = 0.0f;
    for (int h = tid; h < HD; h += 256) {
        float2 w = ((const float2*)W2)[h];
        s0 += w.x; s1 += w.y;
    }
    #pragma unroll
    for (int m = 1; m < 64; m <<= 1) {
        s0 += __shfl_xor(s0, m, 64);
        s1 += __shfl_xor(s1, m, 64);
    }
    if ((tid & 63) == 0) { p0[tid >> 6] = s0; p1[tid >> 6] = s1; }
    __syncthreads();
    if (tid == 0) {
        C01[0] = p0[0] + p0[1] + p0[2] + p0[3] + b2[0];
        C01[1] = p1[0] + p1[1] + p1[2] + p1[3] + b2[1];
    }
}

// ---- main: one block = one sample; 4 waves x 1024 hidden each ----
// t = e^{2a}; t *= E[d]; batch inversion (1 rcp / 16 elems, u=1+t folded into fma);
// per-step cross-lane reduce FULLY deferred: one ds_write_b64/step, chunked
// block reduce every CH steps, epilogue after the d-loop.
__global__ __launch_bounds__(256) void qnade_main(
    const float* __restrict__ x, const float* __restrict__ b1,
    const float* __restrict__ W2, const float* __restrict__ Et,
    const float* __restrict__ C01, float* __restrict__ out)
{
    __shared__ float2 parts[CH][256];   // 16 KB chunk buffer
    __shared__ float2 fin[DS];          // final per-step sums

    const int tid  = threadIdx.x;
    const int lane = tid & 63;
    const int wv   = tid >> 6;
    const int n    = blockIdx.x;
    const int hbase = wv * 1024 + lane * 4;   // + q*256 + c

    // W2 columns as (even,odd)-element pairs
    v2f w20[8], w21[8];
    #pragma unroll
    for (int q = 0; q < 4; ++q) {
        const float4* p = (const float4*)(W2 + 2 * (hbase + q * 256));
        float4 A = p[0], B = p[1];
        w20[2*q]   = (v2f){A.x, A.z};  w21[2*q]   = (v2f){A.y, A.w};
        w20[2*q+1] = (v2f){B.x, B.z};  w21[2*q+1] = (v2f){B.y, B.w};
    }

    // t0 = e^{2*b1}
    v2f t2[8];
    #pragma unroll
    for (int q = 0; q < 4; ++q) {
        float4 b = *(const float4*)(b1 + hbase + q * 256);
        t2[2*q]   = (v2f){__builtin_amdgcn_exp2f(b.x * C2L), __builtin_amdgcn_exp2f(b.y * C2L)};
        t2[2*q+1] = (v2f){__builtin_amdgcn_exp2f(b.z * C2L), __builtin_amdgcn_exp2f(b.w * C2L)};
    }

    const float xv = x[n * DS + lane];
    const unsigned long long msk = __ballot(xv > 0.0f);   // wave-uniform (same for all 4 waves)

    int d = 0;
    for (int c = 0; c < NCH; ++c) {
        #pragma unroll 2
        for (int s8 = 0; s8 < CH; ++s8, ++d) {
            // wave-uniform scalar offset: sign select + row — SGPR-side addressing
            const unsigned uoff = (((msk >> d) & 1ull) ? 0u : (unsigned)(DS * HD)) + d * HD;
            const float* E = Et + uoff + hbase;
            float4 e0 = *(const float4*)(E);
            float4 e1 = *(const float4*)(E + 256);
            float4 e2 = *(const float4*)(E + 512);
            float4 e3 = *(const float4*)(E + 768);

            // prefix products of (1+t), u never materialized
            v2f p2[8];
            p2[0] = pk_add(t2[0], (v2f){1.0f, 1.0f});
            #pragma unroll
            for (int j = 1; j < 8; ++j) p2[j] = pk_fma(p2[j - 1], t2[j], p2[j - 1]);

            // one reciprocal for all 16 elements
            float P = p2[7].x * p2[7].y;
            float R = __builtin_amdgcn_rcpf(P);
            v2f RR = (v2f){R * p2[7].y, R * p2[7].x};

            // fused recovery + dot (r consumed as produced)
            v2f acc0, acc1;
            {
                v2f r = pk_mul(RR, p2[6]);
                acc0 = pk_mul(r, w20[7]);
                acc1 = pk_mul(r, w21[7]);
                RR = pk_fma(RR, t2[7], RR);
            }
            #pragma unroll
            for (int j = 6; j >= 1; --j) {
                v2f r = pk_mul(RR, p2[j - 1]);
                acc0 = pk_fma(r, w20[j], acc0);
                acc1 = pk_fma(r, w21[j], acc1);
                RR = pk_fma(RR, t2[j], RR);
            }
            acc0 = pk_fma(RR, w20[0], acc0);
            acc1 = pk_fma(RR, w21[0], acc1);

            // advance state: t *= e (site d visible for step d+1)
            t2[0] = pk_mul(t2[0], (v2f){e0.x, e0.y});
            t2[1] = pk_mul(t2[1], (v2f){e0.z, e0.w});
            t2[2] = pk_mul(t2[2], (v2f){e1.x, e1.y});
            t2[3] = pk_mul(t2[3], (v2f){e1.z, e1.w});
            t2[4] = pk_mul(t2[4], (v2f){e2.x, e2.y});
            t2[5] = pk_mul(t2[5], (v2f){e2.z, e2.w});
            t2[6] = pk_mul(t2[6], (v2f){e3.x, e3.y});
            t2[7] = pk_mul(t2[7], (v2f){e3.z, e3.w});

            // ONE LDS store per step — no cross-lane chain in the hot loop
            parts[s8][tid] = make_float2(acc0.x + acc0.y, acc1.x + acc1.y);
        }

        __syncthreads();
        // chunk reduce: 32 threads per step; strided b64 reads (2-way = free)
        {
            const int sr = tid >> 5;          // step-in-chunk 0..7
            const int k  = tid & 31;
            v2f s = (v2f){0.0f, 0.0f};
            #pragma unroll
            for (int j = 0; j < 8; ++j) {
                float2 v = parts[sr][k + 32 * j];
                s = pk_add(s, (v2f){v.x, v.y});
            }
            s = pk_add(s, swz_xor<0x041F>(s));   // xor 1
            s = pk_add(s, swz_xor<0x081F>(s));   // xor 2
            s = pk_add(s, swz_xor<0x101F>(s));   // xor 4
            s = pk_add(s, swz_xor<0x201F>(s));   // xor 8
            s = pk_add(s, swz_xor<0x401F>(s));   // xor 16
            if (k == 0) fin[c * CH + sr] = make_float2(s.x, s.y);
        }
        __syncthreads();
    }

    // deferred epilogue: lane d of wave 0 handles step d
    if (tid < DS) {
        const int dd = tid;
        float2 sv = fin[dd];
        float dot0 = __builtin_fmaf(-2.0f, sv.x, C01[0]);
        float dot1 = __builtin_fmaf(-2.0f, sv.y, C01[1]);
        float o0 = fast_tanh(dot0);
        float o1 = fast_tanh(dot1);
        float nrm = sqrtf(__builtin_fmaf(o0, o0, o1 * o1));
        nrm = fmaxf(nrm, 1e-12f);
        float sel = (x[n * DS + dd] > 0.0f) ? o0 : o1;
        float v = sel * __builtin_amdgcn_rcpf(nrm);
        v *= __shfl_xor(v, 1, 64);
        v *= __shfl_xor(v, 2, 64);
        v *= __shfl_xor(v, 4, 64);
        v *= __shfl_xor(v, 8, 64);
        v *= __shfl_xor(v, 16, 64);
        v *= __shfl_xor(v, 32, 64);
        if (tid == 0) out[n] = v;
    }
}

// ---- fallback if ws too small ----
__global__ __launch_bounds__(256) void qnade_fallback(
    const float* __restrict__ x, const float* __restrict__ W1,
    const float* __restrict__ b1, const float* __restrict__ W2,
    const float* __restrict__ b2, float* __restrict__ out)
{
    __shared__ __align__(16) float w20s[HD];
    __shared__ __align__(16) float w21s[HD];
    const int tid = threadIdx.x;
    for (int i = tid; i < HD; i += 256) {
        float2 w = ((const float2*)W2)[i];
        w20s[i] = w.x;
        w21s[i] = w.y;
    }
    const int lane = tid & 63;
    const int wv   = tid >> 6;
    const int n    = (blockIdx.x << 2) + wv;
    const float b20 = b2[0];
    const float b21 = b2[1];
    const float xv = x[n * DS + lane];
    float4 a[16];
    const float4* b1v = (const float4*)b1;
    #pragma unroll
    for (int q = 0; q < 16; ++q) a[q] = b1v[q * 64 + lane];
    __syncthreads();
    const float4* w20v = (const float4*)w20s;
    const float4* w21v = (const float4*)w21s;
    float wav = 1.0f;
    for (int d = 0; d < DS; ++d) {
        const float xd = __shfl(xv, d, 64);
        const float4* w1v = (const float4*)(W1 + d * HD);
        float dot0 = 0.0f, dot1 = 0.0f;
        #pragma unroll
        for (int q = 0; q < 16; ++q) {
            float4 w1 = w1v[q * 64 + lane];
            float4 av = a[q];
            float h0 = fast_tanh(av.x);
            float h1 = fast_tanh(av.y);
            float h2 = fast_tanh(av.z);
            float h3 = fast_tanh(av.w);
            float4 c0 = w20v[q * 64 + lane];
            float4 c1 = w21v[q * 64 + lane];
            dot0 = fmaf(h0, c0.x, dot0); dot0 = fmaf(h1, c0.y, dot0);
            dot0 = fmaf(h2, c0.z, dot0); dot0 = fmaf(h3, c0.w, dot0);
            dot1 = fmaf(h0, c1.x, dot1); dot1 = fmaf(h1, c1.y, dot1);
            dot1 = fmaf(h2, c1.z, dot1); dot1 = fmaf(h3, c1.w, dot1);
            av.x = fmaf(xd, w1.x, av.x); av.y = fmaf(xd, w1.y, av.y);
            av.z = fmaf(xd, w1.z, av.z); av.w = fmaf(xd, w1.w, av.w);
            a[q] = av;
        }
        #pragma unroll
        for (int m = 1; m < 64; m <<= 1) {
            dot0 += __shfl_xor(dot0, m, 64);
            dot1 += __shfl_xor(dot1, m, 64);
        }
        float o0 = fast_tanh(dot0 + b20);
        float o1 = fast_tanh(dot1 + b21);
        float nrm = sqrtf(fmaf(o0, o0, o1 * o1));
        nrm = fmaxf(nrm, 1e-12f);
        float sel = (xd > 0.0f) ? o0 : o1;
        wav *= sel / nrm;
    }
    out[n] = wav;
}

extern "C" void kernel_launch(void* const* d_in, const int* in_sizes, int n_in,
                              void* d_out, int out_size, void* d_ws, size_t ws_size,
                              hipStream_t stream) {
    const float* x  = (const float*)d_in[0];
    const float* W1 = (const float*)d_in[1];
    const float* b1 = (const float*)d_in[2];
    const float* W2 = (const float*)d_in[3];
    const float* b2 = (const float*)d_in[4];
    float* out = (float*)d_out;

    const size_t need = (size_t)(2 * DS * HD + 2) * sizeof(float);
    if (ws_size >= need) {
        float* Et  = (float*)d_ws;           // [2][DS][HD]
        float* C01 = Et + 2 * DS * HD;
        hipLaunchKernelGGL(qnade_prep_E, dim3(DS * HD / 256), dim3(256), 0, stream, W1, Et);
        hipLaunchKernelGGL(qnade_prep_S, dim3(1), dim3(256), 0, stream, W2, b2, C01);
        hipLaunchKernelGGL(qnade_main, dim3(NS), dim3(256), 0, stream, x, b1, W2, Et, C01, out);
    } else {
        hipLaunchKernelGGL(qnade_fallback, dim3(NS / 4), dim3(256), 0, stream, x, W1, b1, W2, b2, out);
    }
}